// Round 8
// baseline (26.949 us; speedup 1.0000x reference)
//
#include <hip/hip_runtime.h>
#include <stdint.h>

#define BB      512
#define NCROPS  5
#define TT      8192
#define THREADS 512
#define WAVES   8
#define HPAD    257   // 256 bins + 1 pad word -> cross-wave bank decorrelation

// Order-preserving f32 -> u32 transform (ascending).
// Every real float maps to a key > 0, so 0u is a safe "masked" sentinel.
__device__ __forceinline__ uint32_t f2ord(float f) {
    uint32_t b = __float_as_uint(f);
    return (b & 0x80000000u) ? ~b : (b | 0x80000000u);
}
__device__ __forceinline__ float ord2f(uint32_t u) {
    uint32_t b = (u & 0x80000000u) ? (u & 0x7FFFFFFFu) : ~u;
    return __uint_as_float(b);
}

#define FOR4(OP) OP(u0) OP(u1) OP(u2) OP(u3)

// ---- building-block macros (reference enclosing-scope vars) ----
#define LOADJ(BASE, SL, A0,A1,A2,A3,A4, J, PRED) \
    const bool PRED = (4 * (tid + (J) * THREADS) < (SL)); \
    float4 A0, A1, A2, A3, A4; \
    if (PRED) { \
        const int t4 = tid + (J) * THREADS; \
        A0 = *reinterpret_cast<const float4*>((BASE) + 0 * TT + 4 * t4); \
        A1 = *reinterpret_cast<const float4*>((BASE) + 1 * TT + 4 * t4); \
        A2 = *reinterpret_cast<const float4*>((BASE) + 2 * TT + 4 * t4); \
        A3 = *reinterpret_cast<const float4*>((BASE) + 3 * TT + 4 * t4); \
        A4 = *reinterpret_cast<const float4*>((BASE) + 4 * TT + 4 * t4); \
    }

#define KEYJ(DST, SL, A0,A1,A2,A3,A4, J, PRED) \
    if (PRED) { \
        const int t0 = 4 * (tid + (J) * THREADS); \
        float4 m; \
        m.x = (A0.x + A1.x + A2.x + A3.x + A4.x) * 0.2f; \
        m.y = (A0.y + A1.y + A2.y + A3.y + A4.y) * 0.2f; \
        m.z = (A0.z + A1.z + A2.z + A3.z + A4.z) * 0.2f; \
        m.w = (A0.w + A1.w + A2.w + A3.w + A4.w) * 0.2f; \
        DST.x = f2ord(m.x); \
        DST.y = (t0 + 1 < (SL)) ? f2ord(m.y) : 0u; \
        DST.z = (t0 + 2 < (SL)) ? f2ord(m.z) : 0u; \
        DST.w = (t0 + 3 < (SL)) ? f2ord(m.w) : 0u; \
    } else { DST.x = 0u; DST.y = 0u; DST.z = 0u; DST.w = 0u; }

#define MAXOP(V) mx = max(mx, max(max(V.x, V.y), max(V.z, V.w)));
#define H0(X)    if ((X) != 0u) atomicAdd(&h[(X) >> 24], 1u);
#define H0V(V)   H0(V.x) H0(V.y) H0(V.z) H0(V.w)
#define HR(X)    if ((X) != 0u && ((X) >> shp) == p) atomicAdd(&h[((X) >> shd) & 255u], 1u);
#define HRV(V)   HR(V.x) HR(V.y) HR(V.z) HR(V.w)

// k-th largest key of {u0..u3} across the block -> THR
#define SELECT(THR, KK) { \
    if ((KK) == 1) { \
        uint32_t mx = 0u; \
        FOR4(MAXOP) \
        for (int off = 32; off; off >>= 1) { \
            const uint32_t o = (uint32_t)__shfl_down((int)mx, off); \
            mx = max(mx, o); \
        } \
        if (lane == 0) s_m[wave] = mx; \
        __syncthreads(); \
        uint32_t rowmax = s_m[0]; \
        for (int w = 1; w < WAVES; ++w) rowmax = max(rowmax, s_m[w]); \
        THR = rowmax; \
    } else { \
        uint32_t p = 0u, kr = (uint32_t)(KK); \
        for (int r = 0; r < 4; ++r) { \
            uint32_t* h = &hist[r & 1][wave][0]; \
            if (r == 0) { FOR4(H0V) } \
            else { \
                const int shp = 32 - 8 * r; \
                const int shd = shp - 8; \
                FOR4(HRV) \
            } \
            __syncthreads(); \
            if (wave == 0) { \
                uint32_t t0s = 0u, t1s = 0u, t2s = 0u, t3s = 0u; \
                for (int w = 0; w < WAVES; ++w) { \
                    const uint32_t* hw = &hist[r & 1][w][0]; \
                    t0s += hw[4 * lane + 0]; \
                    t1s += hw[4 * lane + 1]; \
                    t2s += hw[4 * lane + 2]; \
                    t3s += hw[4 * lane + 3]; \
                } \
                const uint32_t s = t0s + t1s + t2s + t3s; \
                uint32_t suf = s; \
                for (int off = 1; off < 64; off <<= 1) { \
                    const uint32_t v = (uint32_t)__shfl_down((int)suf, off); \
                    if (lane + off < 64) suf += v; \
                } \
                const uint32_t E  = suf - s; \
                const uint32_t T3 = E  + t3s; \
                const uint32_t T2 = T3 + t2s; \
                const uint32_t T1 = T2 + t1s; \
                const uint32_t T0 = T1 + t0s; \
                const unsigned long long bal = __ballot(T0 >= kr); \
                const int L = 63 - __clzll(bal); \
                if (lane == L) { \
                    uint32_t j, Tj, tj; \
                    if      (T3 >= kr) { j = 3u; Tj = T3; tj = t3s; } \
                    else if (T2 >= kr) { j = 2u; Tj = T2; tj = t2s; } \
                    else if (T1 >= kr) { j = 1u; Tj = T1; tj = t1s; } \
                    else               { j = 0u; Tj = T0; tj = t0s; } \
                    bc_p = (p << 8) | (uint32_t)(4 * lane) | j; \
                    bc_k = kr - (Tj - tj); \
                } \
            } else { \
                /* unconditional: also r=3, so hist[0] is clean for the next row */ \
                uint32_t* hz = &hist[(r + 1) & 1][0][0]; \
                for (int i = tid - 64; i < WAVES * HPAD; i += (THREADS - 64)) hz[i] = 0u; \
            } \
            __syncthreads(); \
            p  = bc_p; \
            kr = bc_k; \
        } \
        THR = p; \
    } }

#define SUMOP(V) \
    if (V.x >= _thr) { sg += ord2f(V.x); cg++; } \
    if (V.y >= _thr) { sg += ord2f(V.y); cg++; } \
    if (V.z >= _thr) { sg += ord2f(V.z); cg++; } \
    if (V.w >= _thr) { sg += ord2f(V.w); cg++; }

#define EPILOGUE(THR, KK, LB, ROW) { \
    const uint32_t _thr = (THR); \
    float sg = 0.f; int cg = 0; \
    FOR4(SUMOP) \
    for (int off = 32; off; off >>= 1) { \
        sg += __shfl_down(sg, off); \
        cg += __shfl_down(cg, off); \
    } \
    if (lane == 0) { s_s[wave] = sg; s_c[wave] = cg; } \
    __syncthreads(); \
    if (tid == 0) { \
        float S = 0.f; int C = 0; \
        for (int w = 0; w < WAVES; ++w) { S += s_s[w]; C += s_c[w]; } \
        const float kf   = ord2f(_thr); \
        const float topk = S - (float)(C - (KK)) * kf; \
        const float v    = topk / (float)(KK); \
        const float y    = (float)(LB); \
        const float la   = fmaxf(v, 0.f) + log1pf(expf(-fabsf(v))); \
        row_loss[ROW] = la - v * y; \
    } }

__global__ __launch_bounds__(THREADS, 2) void topk_loss_pairs(
    const float* __restrict__ scores, const int* __restrict__ label,
    const int* __restrict__ seqlen, float* __restrict__ row_loss)
{
    const int tid  = threadIdx.x;
    const int lane = tid & 63;
    const int wave = tid >> 6;
    const int rA   = blockIdx.x;          // 0..255
    const int rB   = blockIdx.x + 256;    // 256..511

    const int slA = seqlen[rA], lbA = label[rA];
    const int slB = seqlen[rB], lbB = label[rB];
    const int kA  = (lbA == 0) ? 1 : (slA / 16 + 1);
    const int kB  = (lbB == 0) ? 1 : (slB / 16 + 1);

    __shared__ uint32_t hist[2][WAVES][HPAD];   // ~16.4 KB, double-buffered
    __shared__ uint32_t bc_p, bc_k;
    __shared__ uint32_t s_m[WAVES];
    __shared__ float    s_s[WAVES];
    __shared__ int      s_c[WAVES];
    // Occupancy limiter: 1 block/CU -> 256 blocks spread over all 256 CUs,
    // single generation, no inter-generation serialization.
    __shared__ uint32_t s_pad[17000];           // 68 KB
    if (slA == -2147483647) s_pad[tid] = 0u;    // opaque; never true

    const float* baseA = scores + (size_t)rA * NCROPS * TT;
    const float* baseB = scores + (size_t)rB * NCROPS * TT;

    // ---- issue row-A loads (predicated, all in flight) ----
    LOADJ(baseA, slA, a0,a1,a2,a3,a4, 0, pa0)
    LOADJ(baseA, slA, b0,b1,b2,b3,b4, 1, pa1)
    LOADJ(baseA, slA, c0,c1,c2,c3,c4, 2, pa2)
    LOADJ(baseA, slA, d0,d1,d2,d3,d4, 3, pa3)

    { // zero hist buffer 0 while A loads fly
        uint32_t* hz = &hist[0][0][0];
        for (int i = tid; i < WAVES * HPAD; i += THREADS) hz[i] = 0u;
    }
    __syncthreads();

    // ---- row-A keys ----
    uint4 u0, u1, u2, u3;
    KEYJ(u0, slA, a0,a1,a2,a3,a4, 0, pa0)
    KEYJ(u1, slA, b0,b1,b2,b3,b4, 1, pa1)
    KEYJ(u2, slA, c0,c1,c2,c3,c4, 2, pa2)
    KEYJ(u3, slA, d0,d1,d2,d3,d4, 3, pa3)

    // ---- issue row-B loads NOW: their HBM latency hides under select-A ----
    LOADJ(baseB, slB, e0,e1,e2,e3,e4, 0, pb0)
    LOADJ(baseB, slB, f0,f1,f2,f3,f4, 1, pb1)
    LOADJ(baseB, slB, g0,g1,g2,g3,g4, 2, pb2)
    LOADJ(baseB, slB, h0,h1,h2,h3,h4, 3, pb3)

    // ---- select + epilogue for row A ----
    uint32_t thrA;
    SELECT(thrA, kA)
    EPILOGUE(thrA, kA, lbA, rA)

    // ---- row-B keys (loads already landed during select-A) ----
    KEYJ(u0, slB, e0,e1,e2,e3,e4, 0, pb0)
    KEYJ(u1, slB, f0,f1,f2,f3,f4, 1, pb1)
    KEYJ(u2, slB, g0,g1,g2,g3,g4, 2, pb2)
    KEYJ(u3, slB, h0,h1,h2,h3,h4, 3, pb3)

    // hist[0] is clean here: fast path never dirtied it; radix re-zeroed it at r=3.
    uint32_t thrB;
    SELECT(thrB, kB)
    EPILOGUE(thrB, kB, lbB, rB)
}

__global__ __launch_bounds__(256) void reduce_loss(
    const float* __restrict__ row_loss, float* __restrict__ out)
{
    const int tid = threadIdx.x;
    float v = row_loss[tid] + row_loss[tid + 256];
    #pragma unroll
    for (int off = 32; off; off >>= 1) v += __shfl_down(v, off);
    __shared__ float s[4];
    if ((tid & 63) == 0) s[tid >> 6] = v;
    __syncthreads();
    if (tid == 0) out[0] = (s[0] + s[1] + s[2] + s[3]) * (1.0f / 512.0f);
}

extern "C" void kernel_launch(void* const* d_in, const int* in_sizes, int n_in,
                              void* d_out, int out_size, void* d_ws, size_t ws_size,
                              hipStream_t stream) {
    const float* scores = (const float*)d_in[0];
    const int*   label  = (const int*)d_in[1];
    const int*   seqlen = (const int*)d_in[2];
    float* out      = (float*)d_out;
    float* row_loss = (float*)d_ws;   // 512 floats

    topk_loss_pairs<<<BB / 2, THREADS, 0, stream>>>(scores, label, seqlen, row_loss);
    reduce_loss<<<1, 256, 0, stream>>>(row_loss, out);
}